// Round 1
// baseline (441.221 us; speedup 1.0000x reference)
//
#include <hip/hip_runtime.h>

#define NZ 32768
#define KE 8192
#define DD 256
#define NCHUNK 4
#define CH (KE / NCHUNK)     // 2048 codes per chunk
#define NSLICE (NCHUNK * 2)  // 8 partial slices
#define ITERS ((CH / 128) * 8)
#define THR_GAP 0.05f
#define BIASF 128.0f

typedef __attribute__((ext_vector_type(8))) _Float16 f16x8;
typedef __attribute__((ext_vector_type(4))) float f32x4;
typedef unsigned int uint32;

// ---------------------------------------------------------------- utilities

__device__ __forceinline__ float wave_reduce_sum(float v) {
#pragma unroll
  for (int m = 32; m >= 1; m >>= 1) v += __shfl_xor(v, m, 64);
  return v;
}

// ---------------------------------------------------------------- fused fp32->fp16 + row-square
__global__ void convsq_kernel(const float* __restrict__ src, unsigned short* __restrict__ dst,
                              float* __restrict__ sq) {
  const int row = blockIdx.x * 4 + (threadIdx.x >> 6);
  const int lane = threadIdx.x & 63;
  const float4 v = *reinterpret_cast<const float4*>(src + (size_t)row * DD + lane * 4);
  alignas(8) _Float16 hv[4] = {(_Float16)v.x, (_Float16)v.y, (_Float16)v.z, (_Float16)v.w};
  *reinterpret_cast<uint2*>(dst + (size_t)row * DD + lane * 4) =
      *reinterpret_cast<const uint2*>(hv);
  float s = (v.x * v.x + v.y * v.y) + (v.z * v.z + v.w * v.w);
  s = wave_reduce_sum(s);
  if (lane == 0) sq[row] = s;
}

// out[0] = sum(ema_cluster_size)
__global__ void sema_kernel(const float* __restrict__ ema_cs, float* __restrict__ out) {
  __shared__ float red[256];
  float s = 0.f;
  for (int i = threadIdx.x; i < KE; i += 256) s += ema_cs[i];
  red[threadIdx.x] = s;
  __syncthreads();
  for (int off = 128; off >= 1; off >>= 1) {
    if (threadIdx.x < off) red[threadIdx.x] += red[threadIdx.x + off];
    __syncthreads();
  }
  if (threadIdx.x == 0) out[0] = red[0];
}

// ---------------------------------------------------------------- MFMA argmin GEMM
// 128x128 tile, 4 waves 2x2, BK=32, single-pass fp16 MFMA.
// r13: BOTH A and B stream through 2x8KB LDS double-buffers (LDS 80KB -> 32KB,
// occupancy 2 -> 3 blocks/CU). A is re-read per column tile (L2-hot, HBM at 2%).
// Top-2 trackers packed into u32 keys (biased-positive float bits | 6-bit meta)
// to free 16 VGPRs so 3 waves/SIMD fits; decoded to the original (float, code)
// format before the unchanged cross-lane merge / pt store.

#define LSTR 32

#define LOADB(RS, itv)                                                          \
  if ((itv) < ITERS) {                                                          \
    const int k1_ = ((itv) & 7) * 32;                                           \
    const size_t bo_ = (size_t)((itv) >> 3) * 128 * DD + k1_;                   \
    RS##b0 = *reinterpret_cast<const uint4*>(ef + boff0 + bo_);                 \
    RS##b1 = *reinterpret_cast<const uint4*>(ef + boff1 + bo_);                 \
  }

#define WRITEB(buf, RS)                                                         \
  *reinterpret_cast<uint4*>(&ldsB[buf][ur][usw]) = RS##b0;                      \
  *reinterpret_cast<uint4*>(&ldsB[buf][ur + 64][usw]) = RS##b1;

#define LOADA(RS, itv)                                                          \
  if ((itv) < ITERS) {                                                          \
    const int ka_ = ((itv) & 7) * 32;                                           \
    RS##a0 = *reinterpret_cast<const uint4*>(zf + aoff0 + ka_);                 \
    RS##a1 = *reinterpret_cast<const uint4*>(zf + aoff1 + ka_);                 \
  }

#define WRITEA(buf, RS)                                                         \
  *reinterpret_cast<uint4*>(&ldsA[buf][ur][usw]) = RS##a0;                      \
  *reinterpret_cast<uint4*>(&ldsA[buf][ur + 64][usw]) = RS##a1;

__launch_bounds__(256, 3)
__global__ void mfma_argmin_kernel(const unsigned short* __restrict__ zf,
                                   const unsigned short* __restrict__ ef,
                                   const float* __restrict__ e2,
                                   float4* __restrict__ pt) {
  __shared__ unsigned short ldsA[2][128][LSTR];  // A dbuf: 16384 B
  __shared__ unsigned short ldsB[2][128][LSTR];  // B dbuf: 16384 B
  const int bid = blockIdx.x;
  const int c = (bid & 7) >> 1;                    // chunk 0..3 (2 XCDs/chunk)
  const int mblk = ((bid >> 3) << 1) | (bid & 1);  // 0..255
  const int row0 = mblk * 128;
  const int cbase = c * CH;
  const int tid = threadIdx.x;
  const int wid = tid >> 6, lane = tid & 63;
  const int wr = wid >> 1, wc = wid & 1;
  const int lg = lane >> 4, l15 = lane & 15;

  const int ur = tid >> 2;
  const int usw = (((tid & 3) ^ ((ur >> 1) & 3)) << 3);
  const int csw = ((lg ^ ((l15 >> 1) & 3)) << 3);
  const size_t aoff0 = (size_t)(row0 + ur) * DD + (tid & 3) * 8;
  const size_t aoff1 = aoff0 + (size_t)64 * DD;
  const size_t boff0 = (size_t)(cbase + ur) * DD + (tid & 3) * 8;
  const size_t boff1 = boff0 + (size_t)64 * DD;

  // packed top-2 trackers: key = (float_bits(v + BIASF) & ~63) | (tile<<2 | j)
  uint32 k1[4][4], k2[4][4];
#pragma unroll
  for (int i = 0; i < 4; ++i)
#pragma unroll
    for (int r = 0; r < 4; ++r) { k1[i][r] = 0xFFFFFFFFu; k2[i][r] = 0xFFFFFFFFu; }

  f32x4 acc[4][4];

  uint4 p0_a0, p0_a1, p0_b0, p0_b1, p1_a0, p1_a1, p1_b0, p1_b1;

  // prologue: A(0),B(0) -> buf0; prefetch A(1),B(1) into regs
  LOADA(p0_, 0)
  LOADB(p0_, 0)
  WRITEA(0, p0_)
  WRITEB(0, p0_)
  LOADA(p1_, 1)
  LOADB(p1_, 1)
  __syncthreads();

#define COMPUTE(buf, itv)                                                               \
  {                                                                                     \
    const int ki_ = (itv) & 7;                                                          \
    if (ki_ == 0) {                                                                     \
      _Pragma("unroll") for (int i = 0; i < 4; ++i)                                     \
          _Pragma("unroll") for (int j = 0; j < 4; ++j) acc[i][j] = (f32x4)(0.f);       \
    }                                                                                   \
    f16x8 ah[4], bh[4];                                                                 \
    _Pragma("unroll") for (int x = 0; x < 4; ++x) {                                     \
      ah[x] = *reinterpret_cast<const f16x8*>(&ldsA[buf][wr * 64 + x * 16 + l15][csw]); \
      bh[x] = *reinterpret_cast<const f16x8*>(&ldsB[buf][wc * 64 + x * 16 + l15][csw]); \
    }                                                                                   \
    _Pragma("unroll") for (int i = 0; i < 4; ++i)                                       \
        _Pragma("unroll") for (int j = 0; j < 4; ++j)                                   \
            acc[i][j] = __builtin_amdgcn_mfma_f32_16x16x32_f16(ah[i], bh[j], acc[i][j], 0, 0, 0); \
    if (ki_ == 7) {                                                                     \
      const int col0 = cbase + ((itv) >> 3) * 128;                                      \
      const uint32 tb_ = (uint32)(((itv) >> 3) << 2);                                   \
      _Pragma("unroll") for (int j = 0; j < 4; ++j) {                                   \
        const int code = col0 + wc * 64 + j * 16 + l15;                                 \
        const float e2b = e2[code] + BIASF;                                             \
        const uint32 meta = tb_ | (uint32)j;                                            \
        _Pragma("unroll") for (int i = 0; i < 4; ++i)                                   \
            _Pragma("unroll") for (int r = 0; r < 4; ++r) {                             \
          const float vb = fmaf(-2.f, acc[i][j][r], e2b);                               \
          const uint32 key = (__float_as_uint(vb) & 0xFFFFFFC0u) | meta;                \
          if (key < k1[i][r]) {                                                         \
            k2[i][r] = k1[i][r];                                                        \
            k1[i][r] = key;                                                             \
          } else if (key < k2[i][r]) {                                                  \
            k2[i][r] = key;                                                             \
          }                                                                             \
        }                                                                               \
      }                                                                                 \
    }                                                                                   \
  }

  for (int it = 0; it < ITERS; it += 2) {
    LOADA(p0_, it + 2)
    LOADB(p0_, it + 2)
    WRITEA(1, p1_)
    WRITEB(1, p1_)
    COMPUTE(0, it)
    __syncthreads();
    LOADA(p1_, it + 3)
    LOADB(p1_, it + 3)
    WRITEA(0, p0_)
    WRITEB(0, p0_)
    COMPUTE(1, it + 1)
    __syncthreads();
  }

  // decode packed keys back to (float value, 16-bit global code) pairs
  float bv1[4][4], bv2[4][4];
  uint32 bpi[4][4];
  const uint32 cb_ = (uint32)(cbase + wc * 64 + l15);
#pragma unroll
  for (int i = 0; i < 4; ++i)
#pragma unroll
    for (int r = 0; r < 4; ++r) {
      const uint32 a1 = k1[i][r], a2 = k2[i][r];
      bv1[i][r] = __uint_as_float(a1 & 0xFFFFFFC0u) - BIASF;
      bv2[i][r] = __uint_as_float(a2 & 0xFFFFFFC0u) - BIASF;
      const uint32 c1 = cb_ + ((a1 & 60u) >> 2) * 128u + ((a1 & 3u) << 4);
      const uint32 c2 = cb_ + ((a2 & 60u) >> 2) * 128u + ((a2 & 3u) << 4);
      bpi[i][r] = c1 | (c2 << 16);
    }

  // cross-lane top-2 merge within 16-lane column groups (unchanged)
#pragma unroll
  for (int m = 1; m <= 8; m <<= 1) {
#pragma unroll
    for (int i = 0; i < 4; ++i)
#pragma unroll
      for (int r = 0; r < 4; ++r) {
        const float ov1 = __shfl_xor(bv1[i][r], m, 64);
        const float ov2 = __shfl_xor(bv2[i][r], m, 64);
        const uint32 op = (uint32)__shfl_xor((int)bpi[i][r], m, 64);
        const uint32 ai1 = bpi[i][r] & 0xFFFFu, oi1 = op & 0xFFFFu;
        const bool ol = (ov1 < bv1[i][r]) || (ov1 == bv1[i][r] && oi1 < ai1);
        const float w1 = ol ? ov1 : bv1[i][r];
        const uint32 wi1 = ol ? oi1 : ai1;
        const float w2 = ol ? ov2 : bv2[i][r];
        const uint32 wi2 = ol ? (op >> 16) : (bpi[i][r] >> 16);
        const float l1 = ol ? bv1[i][r] : ov1;
        const uint32 li1 = ol ? ai1 : oi1;
        const bool s2 = (l1 < w2) || (l1 == w2 && li1 < wi2);
        bv1[i][r] = w1;
        bv2[i][r] = s2 ? l1 : w2;
        bpi[i][r] = wi1 | ((s2 ? li1 : wi2) << 16);
      }
  }
  if (l15 == 0) {
    const int slice = c * 2 + wc;
#pragma unroll
    for (int i = 0; i < 4; ++i)
#pragma unroll
      for (int r = 0; r < 4; ++r) {
        const int row = row0 + wr * 64 + i * 16 + lg * 4 + r;
        pt[(size_t)slice * NZ + row] =
            make_float4(bv1[i][r], bv2[i][r], __uint_as_float(bpi[i][r]), 0.f);
      }
  }
}

// ---------------------------------------------------------------- combine + exact fixup + quantize + loss
__global__ void combine_kernel(const float* __restrict__ z, const float* __restrict__ emb,
                               const float* __restrict__ z2, const float* __restrict__ e2,
                               const float4* __restrict__ pt, float* __restrict__ oidx_f,
                               int* __restrict__ oidx_i, float* __restrict__ oq,
                               float* __restrict__ oloss) {
  const int row = blockIdx.x * 4 + (threadIdx.x >> 6);
  const int lane = threadIdx.x & 63;
  const int wid = threadIdx.x >> 6;
  const float4 p = pt[(size_t)(lane & 7) * NZ + row];
  const float v1 = p.x, v2 = p.y;
  const uint32 pk = __float_as_uint(p.z);
  float m = v1;
#pragma unroll
  for (int s = 1; s <= 4; s <<= 1) m = fminf(m, __shfl_xor(m, s, 64));

  const float4 zv = *reinterpret_cast<const float4*>(z + (size_t)row * DD + lane * 4);
  const float z2r = z2[row];
  float bestd = 3.4e38f;
  int besti = KE;
#pragma unroll 1
  for (int cnum = 0; cnum < 16; ++cnum) {
    const int src = (lane & 56) | (cnum >> 1);
    const float vc = __shfl((cnum & 1) ? v2 : v1, src, 64);
    const uint32 pkc = (uint32)__shfl((int)pk, src, 64);
    const int idxc = (cnum & 1) ? (int)(pkc >> 16) : (int)(pkc & 0xFFFFu);
    if (vc < m + THR_GAP) {
      const float4 ev = *reinterpret_cast<const float4*>(emb + (size_t)idxc * DD + lane * 4);
      float s = (zv.x * ev.x + zv.y * ev.y) + (zv.z * ev.z + zv.w * ev.w);
      s = wave_reduce_sum(s);
      const float d = (z2r - 2.f * s) + e2[idxc];
      if (d < bestd || (d == bestd && idxc < besti)) { bestd = d; besti = idxc; }
    }
  }
  if (lane == 0) {
    oidx_f[row] = (float)besti;
    oidx_i[row] = besti;
  }
  // fused quantize + loss (quantized_st == emb[besti] numerically)
  const float4 qv = *reinterpret_cast<const float4*>(emb + (size_t)besti * DD + lane * 4);
  *reinterpret_cast<float4*>(oq + (size_t)row * DD + lane * 4) = qv;
  const float dx = zv.x - qv.x, dy = zv.y - qv.y, dz = zv.z - qv.z, dw = zv.w - qv.w;
  float s = (dx * dx + dy * dy) + (dz * dz + dw * dw);
  s = wave_reduce_sum(s);
  __shared__ float red[4];
  if (lane == 0) red[wid] = s;
  __syncthreads();
  if (threadIdx.x == 0) {
    const float t = (red[0] + red[1]) + (red[2] + red[3]);
    atomicAdd(oloss, t * (1.25f / ((float)NZ * (float)DD)));
  }
}

// ---------------------------------------------------------------- per-code EMA (8 codes/block)
__global__ void perk_kernel(const float* __restrict__ z, const float* __restrict__ ema_cs,
                            const float* __restrict__ ema_es, const int* __restrict__ usage,
                            const int* __restrict__ idx, const float* __restrict__ sema,
                            float* __restrict__ o_emb, float* __restrict__ o_cs,
                            float* __restrict__ o_es, float* __restrict__ o_us) {
  const int k0 = blockIdx.x * 8;
  const int tid = threadIdx.x;
  __shared__ int cnt;
  __shared__ int cnt8[8];
  __shared__ int stot[8];
  __shared__ int rows[2048];
  float acc[8];
#pragma unroll
  for (int q = 0; q < 8; ++q) acc[q] = 0.f;
  if (tid < 8) stot[tid] = 0;
  for (int base = 0; base < NZ; base += 2048) {
    if (tid == 0) cnt = 0;
    if (tid < 8) cnt8[tid] = 0;
    __syncthreads();
#pragma unroll
    for (int t = 0; t < 2048; t += 256) {
      const int r = base + t + tid;
      const int q = idx[r] - k0;
      if ((unsigned)q < 8u) {
        rows[atomicAdd(&cnt, 1)] = (r << 3) | q;
        atomicAdd(&cnt8[q], 1);
      }
    }
    __syncthreads();
    const int cq = cnt;
    if (tid < 8) stot[tid] += cnt8[tid];
    for (int m = 0; m < cq; ++m) {
      const int rr = rows[m];
      const float v = z[(size_t)(rr >> 3) * DD + tid];
      const int q = rr & 7;
#pragma unroll
      for (int qq = 0; qq < 8; ++qq)
        if (qq == q) acc[qq] += v;
    }
    __syncthreads();
  }
  const float n = 0.99f * sema[0] + 0.01f * (float)NZ;
  const float dn = n + (float)KE * 1e-5f;
#pragma unroll
  for (int q = 0; q < 8; ++q) {
    const float ncs = 0.99f * ema_cs[k0 + q] + 0.01f * (float)stot[q];
    const float nes = 0.99f * ema_es[(size_t)(k0 + q) * DD + tid] + 0.01f * acc[q];
    o_es[(size_t)(k0 + q) * DD + tid] = nes;
    o_emb[(size_t)(k0 + q) * DD + tid] = nes / ((ncs + 1e-5f) / dn * n);
  }
  if (tid < 8) {
    o_cs[k0 + tid] = 0.99f * ema_cs[k0 + tid] + 0.01f * (float)stot[tid];
    o_us[k0 + tid] = (float)(usage[k0 + tid] + stot[tid]);
  }
}

// ---------------------------------------------------------------- launch

extern "C" void kernel_launch(void* const* d_in, const int* in_sizes, int n_in,
                              void* d_out, int out_size, void* d_ws, size_t ws_size,
                              hipStream_t stream) {
  const float* z = (const float*)d_in[0];
  const float* emb = (const float*)d_in[1];
  const float* ema_cs = (const float*)d_in[2];
  const float* ema_es = (const float*)d_in[3];
  const int* usage = (const int*)d_in[4];

  float* out = (float*)d_out;
  float* o_idx = out;
  float* o_q = o_idx + NZ;
  float* o_loss = o_q + (size_t)NZ * DD;
  float* o_emb = o_loss + 1;
  float* o_cs = o_emb + (size_t)KE * DD;
  float* o_es = o_cs + KE;
  float* o_us = o_es + (size_t)KE * DD;

  char* w = (char*)d_ws;
  size_t off = 0;
  auto alloc = [&](size_t bytes) -> char* {
    char* r = w + off;
    off = (off + bytes + 255) & ~(size_t)255;
    return r;
  };
  float* ws_e2 = (float*)alloc(KE * 4);
  float* ws_z2 = (float*)alloc(NZ * 4);
  float* ws_sema = (float*)alloc(256);
  int* ws_idx = (int*)alloc(NZ * 4);
  float4* ws_pt = (float4*)alloc((size_t)NSLICE * NZ * 16);
  unsigned short* z_f16 = (unsigned short*)alloc((size_t)NZ * DD * 2);
  unsigned short* e_f16 = (unsigned short*)alloc((size_t)KE * DD * 2);
  (void)ws_size;

  convsq_kernel<<<KE / 4, 256, 0, stream>>>(emb, e_f16, ws_e2);
  convsq_kernel<<<NZ / 4, 256, 0, stream>>>(z, z_f16, ws_z2);
  sema_kernel<<<1, 256, 0, stream>>>(ema_cs, ws_sema);

  mfma_argmin_kernel<<<(NZ / 128) * NCHUNK, 256, 0, stream>>>(z_f16, e_f16, ws_e2, ws_pt);
  hipMemsetAsync(o_loss, 0, sizeof(float), stream);
  combine_kernel<<<NZ / 4, 256, 0, stream>>>(z, emb, ws_z2, ws_e2, ws_pt, o_idx, ws_idx,
                                             o_q, o_loss);
  perk_kernel<<<KE / 8, 256, 0, stream>>>(z, ema_cs, ema_es, usage, ws_idx, ws_sema,
                                          o_emb, o_cs, o_es, o_us);
}

// Round 4
// 431.322 us; speedup vs baseline: 1.0230x; 1.0230x over previous
//
#include <hip/hip_runtime.h>

#define NZ 32768
#define KE 8192
#define DD 256
#define NCHUNK 4
#define CH (KE / NCHUNK)     // 2048 codes per chunk
#define NSLICE (NCHUNK * 2)  // 8 partial slices
#define ITERS ((CH / 128) * 8)
#define THR_GAP 0.05f

typedef __attribute__((ext_vector_type(8))) _Float16 f16x8;
typedef __attribute__((ext_vector_type(4))) float f32x4;
typedef unsigned int uint32;

// ---------------------------------------------------------------- utilities

__device__ __forceinline__ float wave_reduce_sum(float v) {
#pragma unroll
  for (int m = 32; m >= 1; m >>= 1) v += __shfl_xor(v, m, 64);
  return v;
}

// ---------------------------------------------------------------- fused prologue:
// fp32->fp16 + row-square for BOTH emb and z, plus sum(ema_cluster_size),
// in ONE launch (r16: was 3 launches; bodies byte-identical to r12's kernels).
__global__ void prep_kernel(const float* __restrict__ emb, unsigned short* __restrict__ e_dst,
                            float* __restrict__ e_sq, const float* __restrict__ z,
                            unsigned short* __restrict__ z_dst, float* __restrict__ z_sq,
                            const float* __restrict__ ema_cs, float* __restrict__ sema_out) {
  const int gb = blockIdx.x;
  if (gb < (KE / 4) + (NZ / 4)) {
    const float* src;
    unsigned short* dst;
    float* sq;
    int row;
    if (gb < KE / 4) {
      src = emb; dst = e_dst; sq = e_sq;
      row = gb * 4 + (threadIdx.x >> 6);
    } else {
      src = z; dst = z_dst; sq = z_sq;
      row = (gb - KE / 4) * 4 + (threadIdx.x >> 6);
    }
    const int lane = threadIdx.x & 63;
    const float4 v = *reinterpret_cast<const float4*>(src + (size_t)row * DD + lane * 4);
    alignas(8) _Float16 hv[4] = {(_Float16)v.x, (_Float16)v.y, (_Float16)v.z, (_Float16)v.w};
    *reinterpret_cast<uint2*>(dst + (size_t)row * DD + lane * 4) =
        *reinterpret_cast<const uint2*>(hv);
    float s = (v.x * v.x + v.y * v.y) + (v.z * v.z + v.w * v.w);
    s = wave_reduce_sum(s);
    if (lane == 0) sq[row] = s;
  } else {
    // sum(ema_cluster_size) -> sema_out[0]
    __shared__ float red[256];
    float s = 0.f;
    for (int i = threadIdx.x; i < KE; i += 256) s += ema_cs[i];
    red[threadIdx.x] = s;
    __syncthreads();
    for (int off = 128; off >= 1; off >>= 1) {
      if (threadIdx.x < off) red[threadIdx.x] += red[threadIdx.x + off];
      __syncthreads();
    }
    if (threadIdx.x == 0) sema_out[0] = red[0];
  }
}

// ---------------------------------------------------------------- MFMA argmin GEMM (r12 verbatim)
// 128x128 tile, 4 waves 2x2, BK=32, single-pass fp16 MFMA. A-tile persistent
// in LDS (staged once, 0-conflict swizzle); B double-buffered + depth-2
// prefetch; ONE barrier per iteration. Proven 268 us / FETCH 41 MB.

#define LSTR 32

#define LOADB(RS, itv)                                                          \
  if ((itv) < ITERS) {                                                          \
    const int k1_ = ((itv) & 7) * 32;                                           \
    const size_t bo_ = (size_t)((itv) >> 3) * 128 * DD + k1_;                   \
    RS##b0 = *reinterpret_cast<const uint4*>(ef + boff0 + bo_);                 \
    RS##b1 = *reinterpret_cast<const uint4*>(ef + boff1 + bo_);                 \
  }

#define WRITEB(buf, RS)                                                         \
  *reinterpret_cast<uint4*>(&ldsB[buf][ur][usw]) = RS##b0;                      \
  *reinterpret_cast<uint4*>(&ldsB[buf][ur + 64][usw]) = RS##b1;

__launch_bounds__(256, 2)
__global__ void mfma_argmin_kernel(const unsigned short* __restrict__ zf,
                                   const unsigned short* __restrict__ ef,
                                   const float* __restrict__ e2,
                                   float4* __restrict__ pt) {
  __shared__ unsigned short ldsA[8][128][LSTR];  // persistent A: 65536 B
  __shared__ unsigned short ldsB[2][128][LSTR];  // B dbuf: 16384 B
  const int bid = blockIdx.x;
  const int c = (bid & 7) >> 1;                    // chunk 0..3 (2 XCDs/chunk)
  const int mblk = ((bid >> 3) << 1) | (bid & 1);  // 0..255
  const int row0 = mblk * 128;
  const int cbase = c * CH;
  const int tid = threadIdx.x;
  const int wid = tid >> 6, lane = tid & 63;
  const int wr = wid >> 1, wc = wid & 1;
  const int lg = lane >> 4, l15 = lane & 15;

  const int ur = tid >> 2;
  const int usw = (((tid & 3) ^ ((ur >> 1) & 3)) << 3);
  const int csw = ((lg ^ ((l15 >> 1) & 3)) << 3);
  const size_t aoff0 = (size_t)(row0 + ur) * DD + (tid & 3) * 8;
  const size_t aoff1 = aoff0 + (size_t)64 * DD;
  const size_t boff0 = (size_t)(cbase + ur) * DD + (tid & 3) * 8;
  const size_t boff1 = boff0 + (size_t)64 * DD;

  float bv1[4][4], bv2[4][4];
  uint32 bpi[4][4];
#pragma unroll
  for (int i = 0; i < 4; ++i)
#pragma unroll
    for (int r = 0; r < 4; ++r) { bv1[i][r] = 3.4e38f; bv2[i][r] = 3.4e38f; bpi[i][r] = 0; }

  f32x4 acc[4][4];

  uint4 p0_b0, p0_b1, p1_b0, p1_b1;

  // prologue: stage FULL A-tile once; B(it=0) -> buf0; prefetch B(it=1)
#pragma unroll
  for (int ki = 0; ki < 8; ++ki) {
    const uint4 va0 = *reinterpret_cast<const uint4*>(zf + aoff0 + ki * 32);
    const uint4 va1 = *reinterpret_cast<const uint4*>(zf + aoff1 + ki * 32);
    *reinterpret_cast<uint4*>(&ldsA[ki][ur][usw]) = va0;
    *reinterpret_cast<uint4*>(&ldsA[ki][ur + 64][usw]) = va1;
  }
  LOADB(p0_, 0)
  WRITEB(0, p0_)
  LOADB(p1_, 1)
  __syncthreads();

#define COMPUTE(buf, itv)                                                               \
  {                                                                                     \
    const int ki_ = (itv) & 7;                                                          \
    if (ki_ == 0) {                                                                     \
      _Pragma("unroll") for (int i = 0; i < 4; ++i)                                     \
          _Pragma("unroll") for (int j = 0; j < 4; ++j) acc[i][j] = (f32x4)(0.f);       \
    }                                                                                   \
    f16x8 ah[4], bh[4];                                                                 \
    _Pragma("unroll") for (int x = 0; x < 4; ++x) {                                     \
      ah[x] = *reinterpret_cast<const f16x8*>(&ldsA[ki_][wr * 64 + x * 16 + l15][csw]); \
      bh[x] = *reinterpret_cast<const f16x8*>(&ldsB[buf][wc * 64 + x * 16 + l15][csw]); \
    }                                                                                   \
    _Pragma("unroll") for (int i = 0; i < 4; ++i)                                       \
        _Pragma("unroll") for (int j = 0; j < 4; ++j)                                   \
            acc[i][j] = __builtin_amdgcn_mfma_f32_16x16x32_f16(ah[i], bh[j], acc[i][j], 0, 0, 0); \
    if (ki_ == 7) {                                                                     \
      const int col0 = cbase + ((itv) >> 3) * 128;                                      \
      _Pragma("unroll") for (int j = 0; j < 4; ++j) {                                   \
        const int code = col0 + wc * 64 + j * 16 + l15;                                 \
        const float e2f = e2[code];                                                     \
        _Pragma("unroll") for (int i = 0; i < 4; ++i)                                   \
            _Pragma("unroll") for (int r = 0; r < 4; ++r) {                             \
          const float v = fmaf(-2.f, acc[i][j][r], e2f);                                \
          if (v < bv1[i][r]) {                                                          \
            bv2[i][r] = bv1[i][r];                                                      \
            bpi[i][r] = (bpi[i][r] << 16) | (uint32)code;                               \
            bv1[i][r] = v;                                                              \
          } else if (v < bv2[i][r]) {                                                   \
            bv2[i][r] = v;                                                              \
            bpi[i][r] = (bpi[i][r] & 0xFFFFu) | ((uint32)code << 16);                   \
          }                                                                             \
        }                                                                               \
      }                                                                                 \
    }                                                                                   \
  }

  for (int it = 0; it < ITERS; it += 2) {
    LOADB(p0_, it + 2)
    WRITEB(1, p1_)
    COMPUTE(0, it)
    __syncthreads();
    LOADB(p1_, it + 3)
    WRITEB(0, p0_)
    COMPUTE(1, it + 1)
    __syncthreads();
  }

  // cross-lane top-2 merge within 16-lane column groups
#pragma unroll
  for (int m = 1; m <= 8; m <<= 1) {
#pragma unroll
    for (int i = 0; i < 4; ++i)
#pragma unroll
      for (int r = 0; r < 4; ++r) {
        const float ov1 = __shfl_xor(bv1[i][r], m, 64);
        const float ov2 = __shfl_xor(bv2[i][r], m, 64);
        const uint32 op = (uint32)__shfl_xor((int)bpi[i][r], m, 64);
        const uint32 ai1 = bpi[i][r] & 0xFFFFu, oi1 = op & 0xFFFFu;
        const bool ol = (ov1 < bv1[i][r]) || (ov1 == bv1[i][r] && oi1 < ai1);
        const float w1 = ol ? ov1 : bv1[i][r];
        const uint32 wi1 = ol ? oi1 : ai1;
        const float w2 = ol ? ov2 : bv2[i][r];
        const uint32 wi2 = ol ? (op >> 16) : (bpi[i][r] >> 16);
        const float l1 = ol ? bv1[i][r] : ov1;
        const uint32 li1 = ol ? ai1 : oi1;
        const bool s2 = (l1 < w2) || (l1 == w2 && li1 < wi2);
        bv1[i][r] = w1;
        bv2[i][r] = s2 ? l1 : w2;
        bpi[i][r] = wi1 | ((s2 ? li1 : wi2) << 16);
      }
  }
  if (l15 == 0) {
    const int slice = c * 2 + wc;
#pragma unroll
    for (int i = 0; i < 4; ++i)
#pragma unroll
      for (int r = 0; r < 4; ++r) {
        const int row = row0 + wr * 64 + i * 16 + lg * 4 + r;
        pt[(size_t)slice * NZ + row] =
            make_float4(bv1[i][r], bv2[i][r], __uint_as_float(bpi[i][r]), 0.f);
      }
  }
}

// ---------------------------------------------------------------- combine + exact fixup + quantize + loss
__global__ void combine_kernel(const float* __restrict__ z, const float* __restrict__ emb,
                               const float* __restrict__ z2, const float* __restrict__ e2,
                               const float4* __restrict__ pt, float* __restrict__ oidx_f,
                               int* __restrict__ oidx_i, float* __restrict__ oq,
                               float* __restrict__ oloss) {
  const int row = blockIdx.x * 4 + (threadIdx.x >> 6);
  const int lane = threadIdx.x & 63;
  const int wid = threadIdx.x >> 6;
  const float4 p = pt[(size_t)(lane & 7) * NZ + row];
  const float v1 = p.x, v2 = p.y;
  const uint32 pk = __float_as_uint(p.z);
  float m = v1;
#pragma unroll
  for (int s = 1; s <= 4; s <<= 1) m = fminf(m, __shfl_xor(m, s, 64));

  const float4 zv = *reinterpret_cast<const float4*>(z + (size_t)row * DD + lane * 4);
  const float z2r = z2[row];
  float bestd = 3.4e38f;
  int besti = KE;
#pragma unroll 1
  for (int cnum = 0; cnum < 16; ++cnum) {
    const int src = (lane & 56) | (cnum >> 1);
    const float vc = __shfl((cnum & 1) ? v2 : v1, src, 64);
    const uint32 pkc = (uint32)__shfl((int)pk, src, 64);
    const int idxc = (cnum & 1) ? (int)(pkc >> 16) : (int)(pkc & 0xFFFFu);
    if (vc < m + THR_GAP) {
      const float4 ev = *reinterpret_cast<const float4*>(emb + (size_t)idxc * DD + lane * 4);
      float s = (zv.x * ev.x + zv.y * ev.y) + (zv.z * ev.z + zv.w * ev.w);
      s = wave_reduce_sum(s);
      const float d = (z2r - 2.f * s) + e2[idxc];
      if (d < bestd || (d == bestd && idxc < besti)) { bestd = d; besti = idxc; }
    }
  }
  if (lane == 0) {
    oidx_f[row] = (float)besti;
    oidx_i[row] = besti;
  }
  // fused quantize + loss (quantized_st == emb[besti] numerically)
  const float4 qv = *reinterpret_cast<const float4*>(emb + (size_t)besti * DD + lane * 4);
  *reinterpret_cast<float4*>(oq + (size_t)row * DD + lane * 4) = qv;
  const float dx = zv.x - qv.x, dy = zv.y - qv.y, dz = zv.z - qv.z, dw = zv.w - qv.w;
  float s = (dx * dx + dy * dy) + (dz * dz + dw * dw);
  s = wave_reduce_sum(s);
  __shared__ float red[4];
  if (lane == 0) red[wid] = s;
  __syncthreads();
  if (threadIdx.x == 0) {
    const float t = (red[0] + red[1]) + (red[2] + red[3]);
    atomicAdd(oloss, t * (1.25f / ((float)NZ * (float)DD)));
  }
}

// ---------------------------------------------------------------- per-code EMA (8 codes/block)
__global__ void perk_kernel(const float* __restrict__ z, const float* __restrict__ ema_cs,
                            const float* __restrict__ ema_es, const int* __restrict__ usage,
                            const int* __restrict__ idx, const float* __restrict__ sema,
                            float* __restrict__ o_emb, float* __restrict__ o_cs,
                            float* __restrict__ o_es, float* __restrict__ o_us) {
  const int k0 = blockIdx.x * 8;
  const int tid = threadIdx.x;
  __shared__ int cnt;
  __shared__ int cnt8[8];
  __shared__ int stot[8];
  __shared__ int rows[2048];
  float acc[8];
#pragma unroll
  for (int q = 0; q < 8; ++q) acc[q] = 0.f;
  if (tid < 8) stot[tid] = 0;
  for (int base = 0; base < NZ; base += 2048) {
    if (tid == 0) cnt = 0;
    if (tid < 8) cnt8[tid] = 0;
    __syncthreads();
#pragma unroll
    for (int t = 0; t < 2048; t += 256) {
      const int r = base + t + tid;
      const int q = idx[r] - k0;
      if ((unsigned)q < 8u) {
        rows[atomicAdd(&cnt, 1)] = (r << 3) | q;
        atomicAdd(&cnt8[q], 1);
      }
    }
    __syncthreads();
    const int cq = cnt;
    if (tid < 8) stot[tid] += cnt8[tid];
    for (int m = 0; m < cq; ++m) {
      const int rr = rows[m];
      const float v = z[(size_t)(rr >> 3) * DD + tid];
      const int q = rr & 7;
#pragma unroll
      for (int qq = 0; qq < 8; ++qq)
        if (qq == q) acc[qq] += v;
    }
    __syncthreads();
  }
  const float n = 0.99f * sema[0] + 0.01f * (float)NZ;
  const float dn = n + (float)KE * 1e-5f;
#pragma unroll
  for (int q = 0; q < 8; ++q) {
    const float ncs = 0.99f * ema_cs[k0 + q] + 0.01f * (float)stot[q];
    const float nes = 0.99f * ema_es[(size_t)(k0 + q) * DD + tid] + 0.01f * acc[q];
    o_es[(size_t)(k0 + q) * DD + tid] = nes;
    o_emb[(size_t)(k0 + q) * DD + tid] = nes / ((ncs + 1e-5f) / dn * n);
  }
  if (tid < 8) {
    o_cs[k0 + tid] = 0.99f * ema_cs[k0 + tid] + 0.01f * (float)stot[tid];
    o_us[k0 + tid] = (float)(usage[k0 + tid] + stot[tid]);
  }
}

// ---------------------------------------------------------------- launch

extern "C" void kernel_launch(void* const* d_in, const int* in_sizes, int n_in,
                              void* d_out, int out_size, void* d_ws, size_t ws_size,
                              hipStream_t stream) {
  const float* z = (const float*)d_in[0];
  const float* emb = (const float*)d_in[1];
  const float* ema_cs = (const float*)d_in[2];
  const float* ema_es = (const float*)d_in[3];
  const int* usage = (const int*)d_in[4];

  float* out = (float*)d_out;
  float* o_idx = out;
  float* o_q = o_idx + NZ;
  float* o_loss = o_q + (size_t)NZ * DD;
  float* o_emb = o_loss + 1;
  float* o_cs = o_emb + (size_t)KE * DD;
  float* o_es = o_cs + KE;
  float* o_us = o_es + (size_t)KE * DD;

  char* w = (char*)d_ws;
  size_t off = 0;
  auto alloc = [&](size_t bytes) -> char* {
    char* r = w + off;
    off = (off + bytes + 255) & ~(size_t)255;
    return r;
  };
  float* ws_e2 = (float*)alloc(KE * 4);
  float* ws_z2 = (float*)alloc(NZ * 4);
  float* ws_sema = (float*)alloc(256);
  int* ws_idx = (int*)alloc(NZ * 4);
  float4* ws_pt = (float4*)alloc((size_t)NSLICE * NZ * 16);
  unsigned short* z_f16 = (unsigned short*)alloc((size_t)NZ * DD * 2);
  unsigned short* e_f16 = (unsigned short*)alloc((size_t)KE * DD * 2);
  (void)ws_size;

  prep_kernel<<<(KE / 4) + (NZ / 4) + 1, 256, 0, stream>>>(emb, e_f16, ws_e2, z, z_f16,
                                                           ws_z2, ema_cs, ws_sema);

  mfma_argmin_kernel<<<(NZ / 128) * NCHUNK, 256, 0, stream>>>(z_f16, e_f16, ws_e2, ws_pt);
  hipMemsetAsync(o_loss, 0, sizeof(float), stream);
  combine_kernel<<<NZ / 4, 256, 0, stream>>>(z, emb, ws_z2, ws_e2, ws_pt, o_idx, ws_idx,
                                             o_q, o_loss);
  perk_kernel<<<KE / 8, 256, 0, stream>>>(z, ema_cs, ema_es, usage, ws_idx, ws_sema,
                                          o_emb, o_cs, o_es, o_us);
}

// Round 5
// 427.819 us; speedup vs baseline: 1.0313x; 1.0082x over previous
//
#include <hip/hip_runtime.h>

#define NZ 32768
#define KE 8192
#define DD 256
#define NCHUNK 4
#define CH (KE / NCHUNK)     // 2048 codes per chunk
#define NSLICE (NCHUNK * 2)  // 8 partial slices
#define ITERS ((CH / 128) * 8)
#define THR_GAP 0.05f

typedef __attribute__((ext_vector_type(8))) _Float16 f16x8;
typedef __attribute__((ext_vector_type(4))) float f32x4;
typedef unsigned int uint32;

// ---------------------------------------------------------------- utilities

__device__ __forceinline__ float wave_reduce_sum(float v) {
#pragma unroll
  for (int m = 32; m >= 1; m >>= 1) v += __shfl_xor(v, m, 64);
  return v;
}

// ---------------------------------------------------------------- fused prologue:
// fp32->fp16 + row-square for BOTH emb and z, plus sum(ema_cluster_size),
// in ONE launch (r16, proven).
__global__ void prep_kernel(const float* __restrict__ emb, unsigned short* __restrict__ e_dst,
                            float* __restrict__ e_sq, const float* __restrict__ z,
                            unsigned short* __restrict__ z_dst, float* __restrict__ z_sq,
                            const float* __restrict__ ema_cs, float* __restrict__ sema_out) {
  const int gb = blockIdx.x;
  if (gb < (KE / 4) + (NZ / 4)) {
    const float* src;
    unsigned short* dst;
    float* sq;
    int row;
    if (gb < KE / 4) {
      src = emb; dst = e_dst; sq = e_sq;
      row = gb * 4 + (threadIdx.x >> 6);
    } else {
      src = z; dst = z_dst; sq = z_sq;
      row = (gb - KE / 4) * 4 + (threadIdx.x >> 6);
    }
    const int lane = threadIdx.x & 63;
    const float4 v = *reinterpret_cast<const float4*>(src + (size_t)row * DD + lane * 4);
    alignas(8) _Float16 hv[4] = {(_Float16)v.x, (_Float16)v.y, (_Float16)v.z, (_Float16)v.w};
    *reinterpret_cast<uint2*>(dst + (size_t)row * DD + lane * 4) =
        *reinterpret_cast<const uint2*>(hv);
    float s = (v.x * v.x + v.y * v.y) + (v.z * v.z + v.w * v.w);
    s = wave_reduce_sum(s);
    if (lane == 0) sq[row] = s;
  } else {
    __shared__ float red[256];
    float s = 0.f;
    for (int i = threadIdx.x; i < KE; i += 256) s += ema_cs[i];
    red[threadIdx.x] = s;
    __syncthreads();
    for (int off = 128; off >= 1; off >>= 1) {
      if (threadIdx.x < off) red[threadIdx.x] += red[threadIdx.x + off];
      __syncthreads();
    }
    if (threadIdx.x == 0) sema_out[0] = red[0];
  }
}

// ---------------------------------------------------------------- MFMA argmin GEMM
// r17: 64x128 tile (was 128x128). Persistent A shrinks 64->32 KB, LDS/block
// 80->48 KB -> 3 blocks/CU (12 waves/CU, was 8). Co-resident blocks at
// independent phases hide the per-K-step barrier drain that capped r12 at
// ~58% pipe-busy. All machinery (B staging, swizzles, float top-2 tracker,
// merge, pt layout) is r12/r16 text with the wave row-extent halved
// (each wave owns 32x64 out, 8 MFMA/K-step, i-loops 4->2). Outputs should
// be bit-identical to r16.

#define LSTR 32

#define LOADB(RS, itv)                                                          \
  if ((itv) < ITERS) {                                                          \
    const int k1_ = ((itv) & 7) * 32;                                           \
    const size_t bo_ = (size_t)((itv) >> 3) * 128 * DD + k1_;                   \
    RS##b0 = *reinterpret_cast<const uint4*>(ef + boff0 + bo_);                 \
    RS##b1 = *reinterpret_cast<const uint4*>(ef + boff1 + bo_);                 \
  }

#define WRITEB(buf, RS)                                                         \
  *reinterpret_cast<uint4*>(&ldsB[buf][ur][usw]) = RS##b0;                      \
  *reinterpret_cast<uint4*>(&ldsB[buf][ur + 64][usw]) = RS##b1;

__launch_bounds__(256, 3)
__global__ void mfma_argmin_kernel(const unsigned short* __restrict__ zf,
                                   const unsigned short* __restrict__ ef,
                                   const float* __restrict__ e2,
                                   float4* __restrict__ pt) {
  __shared__ unsigned short ldsA[8][64][LSTR];   // persistent A: 32768 B
  __shared__ unsigned short ldsB[2][128][LSTR];  // B dbuf: 16384 B
  const int bid = blockIdx.x;
  const int c = (bid & 7) >> 1;                    // chunk 0..3 (2 XCDs/chunk)
  const int mblk = ((bid >> 3) << 1) | (bid & 1);  // 0..511
  const int row0 = mblk * 64;
  const int cbase = c * CH;
  const int tid = threadIdx.x;
  const int wid = tid >> 6, lane = tid & 63;
  const int wr = wid >> 1, wc = wid & 1;
  const int lg = lane >> 4, l15 = lane & 15;

  const int ur = tid >> 2;
  const int usw = (((tid & 3) ^ ((ur >> 1) & 3)) << 3);
  const int csw = ((lg ^ ((l15 >> 1) & 3)) << 3);
  const size_t aoff0 = (size_t)(row0 + ur) * DD + (tid & 3) * 8;
  const size_t boff0 = (size_t)(cbase + ur) * DD + (tid & 3) * 8;
  const size_t boff1 = boff0 + (size_t)64 * DD;

  float bv1[2][4], bv2[2][4];
  uint32 bpi[2][4];
#pragma unroll
  for (int i = 0; i < 2; ++i)
#pragma unroll
    for (int r = 0; r < 4; ++r) { bv1[i][r] = 3.4e38f; bv2[i][r] = 3.4e38f; bpi[i][r] = 0; }

  f32x4 acc[2][4];

  uint4 p0_b0, p0_b1, p1_b0, p1_b1;

  // prologue: stage FULL A-tile once; B(it=0) -> buf0; prefetch B(it=1)
#pragma unroll
  for (int ki = 0; ki < 8; ++ki) {
    const uint4 va0 = *reinterpret_cast<const uint4*>(zf + aoff0 + ki * 32);
    *reinterpret_cast<uint4*>(&ldsA[ki][ur][usw]) = va0;
  }
  LOADB(p0_, 0)
  WRITEB(0, p0_)
  LOADB(p1_, 1)
  __syncthreads();

#define COMPUTE(buf, itv)                                                               \
  {                                                                                     \
    const int ki_ = (itv) & 7;                                                          \
    if (ki_ == 0) {                                                                     \
      _Pragma("unroll") for (int i = 0; i < 2; ++i)                                     \
          _Pragma("unroll") for (int j = 0; j < 4; ++j) acc[i][j] = (f32x4)(0.f);       \
    }                                                                                   \
    f16x8 ah[2], bh[4];                                                                 \
    _Pragma("unroll") for (int x = 0; x < 2; ++x)                                       \
      ah[x] = *reinterpret_cast<const f16x8*>(&ldsA[ki_][wr * 32 + x * 16 + l15][csw]); \
    _Pragma("unroll") for (int x = 0; x < 4; ++x)                                       \
      bh[x] = *reinterpret_cast<const f16x8*>(&ldsB[buf][wc * 64 + x * 16 + l15][csw]); \
    _Pragma("unroll") for (int i = 0; i < 2; ++i)                                       \
        _Pragma("unroll") for (int j = 0; j < 4; ++j)                                   \
            acc[i][j] = __builtin_amdgcn_mfma_f32_16x16x32_f16(ah[i], bh[j], acc[i][j], 0, 0, 0); \
    if (ki_ == 7) {                                                                     \
      const int col0 = cbase + ((itv) >> 3) * 128;                                      \
      _Pragma("unroll") for (int j = 0; j < 4; ++j) {                                   \
        const int code = col0 + wc * 64 + j * 16 + l15;                                 \
        const float e2f = e2[code];                                                     \
        _Pragma("unroll") for (int i = 0; i < 2; ++i)                                   \
            _Pragma("unroll") for (int r = 0; r < 4; ++r) {                             \
          const float v = fmaf(-2.f, acc[i][j][r], e2f);                                \
          if (v < bv1[i][r]) {                                                          \
            bv2[i][r] = bv1[i][r];                                                      \
            bpi[i][r] = (bpi[i][r] << 16) | (uint32)code;                               \
            bv1[i][r] = v;                                                              \
          } else if (v < bv2[i][r]) {                                                   \
            bv2[i][r] = v;                                                              \
            bpi[i][r] = (bpi[i][r] & 0xFFFFu) | ((uint32)code << 16);                   \
          }                                                                             \
        }                                                                               \
      }                                                                                 \
    }                                                                                   \
  }

  for (int it = 0; it < ITERS; it += 2) {
    LOADB(p0_, it + 2)
    WRITEB(1, p1_)
    COMPUTE(0, it)
    __syncthreads();
    LOADB(p1_, it + 3)
    WRITEB(0, p0_)
    COMPUTE(1, it + 1)
    __syncthreads();
  }

  // cross-lane top-2 merge within 16-lane column groups
#pragma unroll
  for (int m = 1; m <= 8; m <<= 1) {
#pragma unroll
    for (int i = 0; i < 2; ++i)
#pragma unroll
      for (int r = 0; r < 4; ++r) {
        const float ov1 = __shfl_xor(bv1[i][r], m, 64);
        const float ov2 = __shfl_xor(bv2[i][r], m, 64);
        const uint32 op = (uint32)__shfl_xor((int)bpi[i][r], m, 64);
        const uint32 ai1 = bpi[i][r] & 0xFFFFu, oi1 = op & 0xFFFFu;
        const bool ol = (ov1 < bv1[i][r]) || (ov1 == bv1[i][r] && oi1 < ai1);
        const float w1 = ol ? ov1 : bv1[i][r];
        const uint32 wi1 = ol ? oi1 : ai1;
        const float w2 = ol ? ov2 : bv2[i][r];
        const uint32 wi2 = ol ? (op >> 16) : (bpi[i][r] >> 16);
        const float l1 = ol ? bv1[i][r] : ov1;
        const uint32 li1 = ol ? ai1 : oi1;
        const bool s2 = (l1 < w2) || (l1 == w2 && li1 < wi2);
        bv1[i][r] = w1;
        bv2[i][r] = s2 ? l1 : w2;
        bpi[i][r] = wi1 | ((s2 ? li1 : wi2) << 16);
      }
  }
  if (l15 == 0) {
    const int slice = c * 2 + wc;
#pragma unroll
    for (int i = 0; i < 2; ++i)
#pragma unroll
      for (int r = 0; r < 4; ++r) {
        const int row = row0 + wr * 32 + i * 16 + lg * 4 + r;
        pt[(size_t)slice * NZ + row] =
            make_float4(bv1[i][r], bv2[i][r], __uint_as_float(bpi[i][r]), 0.f);
      }
  }
}

// ---------------------------------------------------------------- combine + exact fixup + quantize + loss
__global__ void combine_kernel(const float* __restrict__ z, const float* __restrict__ emb,
                               const float* __restrict__ z2, const float* __restrict__ e2,
                               const float4* __restrict__ pt, float* __restrict__ oidx_f,
                               int* __restrict__ oidx_i, float* __restrict__ oq,
                               float* __restrict__ oloss) {
  const int row = blockIdx.x * 4 + (threadIdx.x >> 6);
  const int lane = threadIdx.x & 63;
  const int wid = threadIdx.x >> 6;
  const float4 p = pt[(size_t)(lane & 7) * NZ + row];
  const float v1 = p.x, v2 = p.y;
  const uint32 pk = __float_as_uint(p.z);
  float m = v1;
#pragma unroll
  for (int s = 1; s <= 4; s <<= 1) m = fminf(m, __shfl_xor(m, s, 64));

  const float4 zv = *reinterpret_cast<const float4*>(z + (size_t)row * DD + lane * 4);
  const float z2r = z2[row];
  float bestd = 3.4e38f;
  int besti = KE;
#pragma unroll 1
  for (int cnum = 0; cnum < 16; ++cnum) {
    const int src = (lane & 56) | (cnum >> 1);
    const float vc = __shfl((cnum & 1) ? v2 : v1, src, 64);
    const uint32 pkc = (uint32)__shfl((int)pk, src, 64);
    const int idxc = (cnum & 1) ? (int)(pkc >> 16) : (int)(pkc & 0xFFFFu);
    if (vc < m + THR_GAP) {
      const float4 ev = *reinterpret_cast<const float4*>(emb + (size_t)idxc * DD + lane * 4);
      float s = (zv.x * ev.x + zv.y * ev.y) + (zv.z * ev.z + zv.w * ev.w);
      s = wave_reduce_sum(s);
      const float d = (z2r - 2.f * s) + e2[idxc];
      if (d < bestd || (d == bestd && idxc < besti)) { bestd = d; besti = idxc; }
    }
  }
  if (lane == 0) {
    oidx_f[row] = (float)besti;
    oidx_i[row] = besti;
  }
  // fused quantize + loss (quantized_st == emb[besti] numerically)
  const float4 qv = *reinterpret_cast<const float4*>(emb + (size_t)besti * DD + lane * 4);
  *reinterpret_cast<float4*>(oq + (size_t)row * DD + lane * 4) = qv;
  const float dx = zv.x - qv.x, dy = zv.y - qv.y, dz = zv.z - qv.z, dw = zv.w - qv.w;
  float s = (dx * dx + dy * dy) + (dz * dz + dw * dw);
  s = wave_reduce_sum(s);
  __shared__ float red[4];
  if (lane == 0) red[wid] = s;
  __syncthreads();
  if (threadIdx.x == 0) {
    const float t = (red[0] + red[1]) + (red[2] + red[3]);
    atomicAdd(oloss, t * (1.25f / ((float)NZ * (float)DD)));
  }
}

// ---------------------------------------------------------------- per-code EMA (8 codes/block)
__global__ void perk_kernel(const float* __restrict__ z, const float* __restrict__ ema_cs,
                            const float* __restrict__ ema_es, const int* __restrict__ usage,
                            const int* __restrict__ idx, const float* __restrict__ sema,
                            float* __restrict__ o_emb, float* __restrict__ o_cs,
                            float* __restrict__ o_es, float* __restrict__ o_us) {
  const int k0 = blockIdx.x * 8;
  const int tid = threadIdx.x;
  __shared__ int cnt;
  __shared__ int cnt8[8];
  __shared__ int stot[8];
  __shared__ int rows[2048];
  float acc[8];
#pragma unroll
  for (int q = 0; q < 8; ++q) acc[q] = 0.f;
  if (tid < 8) stot[tid] = 0;
  for (int base = 0; base < NZ; base += 2048) {
    if (tid == 0) cnt = 0;
    if (tid < 8) cnt8[tid] = 0;
    __syncthreads();
#pragma unroll
    for (int t = 0; t < 2048; t += 256) {
      const int r = base + t + tid;
      const int q = idx[r] - k0;
      if ((unsigned)q < 8u) {
        rows[atomicAdd(&cnt, 1)] = (r << 3) | q;
        atomicAdd(&cnt8[q], 1);
      }
    }
    __syncthreads();
    const int cq = cnt;
    if (tid < 8) stot[tid] += cnt8[tid];
    for (int m = 0; m < cq; ++m) {
      const int rr = rows[m];
      const float v = z[(size_t)(rr >> 3) * DD + tid];
      const int q = rr & 7;
#pragma unroll
      for (int qq = 0; qq < 8; ++qq)
        if (qq == q) acc[qq] += v;
    }
    __syncthreads();
  }
  const float n = 0.99f * sema[0] + 0.01f * (float)NZ;
  const float dn = n + (float)KE * 1e-5f;
#pragma unroll
  for (int q = 0; q < 8; ++q) {
    const float ncs = 0.99f * ema_cs[k0 + q] + 0.01f * (float)stot[q];
    const float nes = 0.99f * ema_es[(size_t)(k0 + q) * DD + tid] + 0.01f * acc[q];
    o_es[(size_t)(k0 + q) * DD + tid] = nes;
    o_emb[(size_t)(k0 + q) * DD + tid] = nes / ((ncs + 1e-5f) / dn * n);
  }
  if (tid < 8) {
    o_cs[k0 + tid] = 0.99f * ema_cs[k0 + tid] + 0.01f * (float)stot[tid];
    o_us[k0 + tid] = (float)(usage[k0 + tid] + stot[tid]);
  }
}

// ---------------------------------------------------------------- launch

extern "C" void kernel_launch(void* const* d_in, const int* in_sizes, int n_in,
                              void* d_out, int out_size, void* d_ws, size_t ws_size,
                              hipStream_t stream) {
  const float* z = (const float*)d_in[0];
  const float* emb = (const float*)d_in[1];
  const float* ema_cs = (const float*)d_in[2];
  const float* ema_es = (const float*)d_in[3];
  const int* usage = (const int*)d_in[4];

  float* out = (float*)d_out;
  float* o_idx = out;
  float* o_q = o_idx + NZ;
  float* o_loss = o_q + (size_t)NZ * DD;
  float* o_emb = o_loss + 1;
  float* o_cs = o_emb + (size_t)KE * DD;
  float* o_es = o_cs + KE;
  float* o_us = o_es + (size_t)KE * DD;

  char* w = (char*)d_ws;
  size_t off = 0;
  auto alloc = [&](size_t bytes) -> char* {
    char* r = w + off;
    off = (off + bytes + 255) & ~(size_t)255;
    return r;
  };
  float* ws_e2 = (float*)alloc(KE * 4);
  float* ws_z2 = (float*)alloc(NZ * 4);
  float* ws_sema = (float*)alloc(256);
  int* ws_idx = (int*)alloc(NZ * 4);
  float4* ws_pt = (float4*)alloc((size_t)NSLICE * NZ * 16);
  unsigned short* z_f16 = (unsigned short*)alloc((size_t)NZ * DD * 2);
  unsigned short* e_f16 = (unsigned short*)alloc((size_t)KE * DD * 2);
  (void)ws_size;

  prep_kernel<<<(KE / 4) + (NZ / 4) + 1, 256, 0, stream>>>(emb, e_f16, ws_e2, z, z_f16,
                                                           ws_z2, ema_cs, ws_sema);

  mfma_argmin_kernel<<<(NZ / 64) * NCHUNK, 256, 0, stream>>>(z_f16, e_f16, ws_e2, ws_pt);
  hipMemsetAsync(o_loss, 0, sizeof(float), stream);
  combine_kernel<<<NZ / 4, 256, 0, stream>>>(z, emb, ws_z2, ws_e2, ws_pt, o_idx, ws_idx,
                                             o_q, o_loss);
  perk_kernel<<<KE / 8, 256, 0, stream>>>(z, ema_cs, ema_es, usage, ws_idx, ws_sema,
                                          o_emb, o_cs, o_es, o_us);
}

// Round 6
// 386.627 us; speedup vs baseline: 1.1412x; 1.1065x over previous
//
#include <hip/hip_runtime.h>

#define NZ 32768
#define KE 8192
#define DD 256
#define NCHUNK 4
#define CH (KE / NCHUNK)     // 2048 codes per chunk
#define NSLICE (NCHUNK * 2)  // 8 partial slices
#define ITERS ((CH / 128) * 8)
#define THR_GAP 0.05f
#define BIASF 128.0f

typedef __attribute__((ext_vector_type(8))) _Float16 f16x8;
typedef __attribute__((ext_vector_type(4))) float f32x4;
typedef unsigned int uint32;

// ---------------------------------------------------------------- utilities

__device__ __forceinline__ float wave_reduce_sum(float v) {
#pragma unroll
  for (int m = 32; m >= 1; m >>= 1) v += __shfl_xor(v, m, 64);
  return v;
}

// ---------------------------------------------------------------- fused prologue:
// fp32->fp16 + row-square for BOTH emb and z, sum(ema_cluster_size), and
// o_loss zeroing (r18: memset launch folded in; per-launch re-zero kept for
// graph-replay safety).
__global__ void prep_kernel(const float* __restrict__ emb, unsigned short* __restrict__ e_dst,
                            float* __restrict__ e_sq, const float* __restrict__ z,
                            unsigned short* __restrict__ z_dst, float* __restrict__ z_sq,
                            const float* __restrict__ ema_cs, float* __restrict__ sema_out,
                            float* __restrict__ o_loss) {
  const int gb = blockIdx.x;
  if (gb < (KE / 4) + (NZ / 4)) {
    const float* src;
    unsigned short* dst;
    float* sq;
    int row;
    if (gb < KE / 4) {
      src = emb; dst = e_dst; sq = e_sq;
      row = gb * 4 + (threadIdx.x >> 6);
    } else {
      src = z; dst = z_dst; sq = z_sq;
      row = (gb - KE / 4) * 4 + (threadIdx.x >> 6);
    }
    const int lane = threadIdx.x & 63;
    const float4 v = *reinterpret_cast<const float4*>(src + (size_t)row * DD + lane * 4);
    alignas(8) _Float16 hv[4] = {(_Float16)v.x, (_Float16)v.y, (_Float16)v.z, (_Float16)v.w};
    *reinterpret_cast<uint2*>(dst + (size_t)row * DD + lane * 4) =
        *reinterpret_cast<const uint2*>(hv);
    float s = (v.x * v.x + v.y * v.y) + (v.z * v.z + v.w * v.w);
    s = wave_reduce_sum(s);
    if (lane == 0) sq[row] = s;
  } else {
    __shared__ float red[256];
    float s = 0.f;
    for (int i = threadIdx.x; i < KE; i += 256) s += ema_cs[i];
    red[threadIdx.x] = s;
    __syncthreads();
    for (int off = 128; off >= 1; off >>= 1) {
      if (threadIdx.x < off) red[threadIdx.x] += red[threadIdx.x + off];
      __syncthreads();
    }
    if (threadIdx.x == 0) {
      sema_out[0] = red[0];
      o_loss[0] = 0.f;
    }
  }
}

// ---------------------------------------------------------------- MFMA argmin GEMM
// r18: 64x128 tile, persistent A (32 KB) + QUAD-buffered B (4x8 KB = 32 KB,
// 64 KB total, 2 blocks/CU). One barrier per TWO K-steps (was one per step):
// within each 2-step window writes touch {B2,B3} while reads touch {B0,B1}
// (or swapped) -- disjoint; cross-window conflicts are barrier-separated.
// r17 proved occupancy 2<->3 blocks is perf-neutral, so the LDS growth is
// free; the barrier count halves (128 -> 64). Tracker is the r13-verbatim
// in-burst packed-key top-2 (proven passing): u32 key = float_bits(v+128)
// &~63 | {tile,j} meta, branchy update, e2 loaded inside the ki==7 burst.

#define LSTR 32

#define LOADB(RS, itv)                                                          \
  if ((itv) < ITERS) {                                                          \
    const int kb_ = ((itv) & 7) * 32;                                           \
    const size_t bo_ = (size_t)((itv) >> 3) * 128 * DD + kb_;                   \
    RS##b0 = *reinterpret_cast<const uint4*>(ef + boff0 + bo_);                 \
    RS##b1 = *reinterpret_cast<const uint4*>(ef + boff1 + bo_);                 \
  }

#define WRITEB(buf, RS)                                                         \
  *reinterpret_cast<uint4*>(&ldsB[buf][ur][usw]) = RS##b0;                      \
  *reinterpret_cast<uint4*>(&ldsB[buf][ur + 64][usw]) = RS##b1;

__launch_bounds__(256, 2)
__global__ void mfma_argmin_kernel(const unsigned short* __restrict__ zf,
                                   const unsigned short* __restrict__ ef,
                                   const float* __restrict__ e2,
                                   float4* __restrict__ pt) {
  __shared__ unsigned short ldsA[8][64][LSTR];   // persistent A: 32768 B
  __shared__ unsigned short ldsB[4][128][LSTR];  // B quad-buffer: 32768 B
  const int bid = blockIdx.x;
  const int c = (bid & 7) >> 1;                    // chunk 0..3 (2 XCDs/chunk)
  const int mblk = ((bid >> 3) << 1) | (bid & 1);  // 0..511
  const int row0 = mblk * 64;
  const int cbase = c * CH;
  const int tid = threadIdx.x;
  const int wid = tid >> 6, lane = tid & 63;
  const int wr = wid >> 1, wc = wid & 1;
  const int lg = lane >> 4, l15 = lane & 15;

  const int ur = tid >> 2;
  const int usw = (((tid & 3) ^ ((ur >> 1) & 3)) << 3);
  const int csw = ((lg ^ ((l15 >> 1) & 3)) << 3);
  const size_t aoff0 = (size_t)(row0 + ur) * DD + (tid & 3) * 8;
  const size_t boff0 = (size_t)(cbase + ur) * DD + (tid & 3) * 8;
  const size_t boff1 = boff0 + (size_t)64 * DD;

  // packed top-2 trackers: key = (float_bits(v + BIASF) & ~63) | (tile<<2 | j)
  uint32 k1[2][4], k2[2][4];
#pragma unroll
  for (int i = 0; i < 2; ++i)
#pragma unroll
    for (int r = 0; r < 4; ++r) { k1[i][r] = 0xFFFFFFFFu; k2[i][r] = 0xFFFFFFFFu; }

  f32x4 acc[2][4];

  uint4 p0_b0, p0_b1, p1_b0, p1_b1;

  // prologue: stage FULL A-tile once; B(0)->buf0, B(1)->buf1; prefetch B(2),B(3)
#pragma unroll
  for (int ki = 0; ki < 8; ++ki) {
    const uint4 va0 = *reinterpret_cast<const uint4*>(zf + aoff0 + ki * 32);
    *reinterpret_cast<uint4*>(&ldsA[ki][ur][usw]) = va0;
  }
  LOADB(p0_, 0)
  WRITEB(0, p0_)
  LOADB(p1_, 1)
  WRITEB(1, p1_)
  LOADB(p0_, 2)
  LOADB(p1_, 3)
  __syncthreads();

#define COMPUTE(buf, itv)                                                               \
  {                                                                                     \
    const int ki_ = (itv) & 7;                                                          \
    if (ki_ == 0) {                                                                     \
      _Pragma("unroll") for (int i = 0; i < 2; ++i)                                     \
          _Pragma("unroll") for (int j = 0; j < 4; ++j) acc[i][j] = (f32x4)(0.f);       \
    }                                                                                   \
    f16x8 ah[2], bh[4];                                                                 \
    _Pragma("unroll") for (int x = 0; x < 2; ++x)                                       \
      ah[x] = *reinterpret_cast<const f16x8*>(&ldsA[ki_][wr * 32 + x * 16 + l15][csw]); \
    _Pragma("unroll") for (int x = 0; x < 4; ++x)                                       \
      bh[x] = *reinterpret_cast<const f16x8*>(&ldsB[buf][wc * 64 + x * 16 + l15][csw]); \
    _Pragma("unroll") for (int i = 0; i < 2; ++i)                                       \
        _Pragma("unroll") for (int j = 0; j < 4; ++j)                                   \
            acc[i][j] = __builtin_amdgcn_mfma_f32_16x16x32_f16(ah[i], bh[j], acc[i][j], 0, 0, 0); \
    if (ki_ == 7) {                                                                     \
      const int col0 = cbase + ((itv) >> 3) * 128;                                      \
      const uint32 tb_ = (uint32)(((itv) >> 3) << 2);                                   \
      _Pragma("unroll") for (int j = 0; j < 4; ++j) {                                   \
        const int code = col0 + wc * 64 + j * 16 + l15;                                 \
        const float e2b = e2[code] + BIASF;                                             \
        const uint32 meta = tb_ | (uint32)j;                                            \
        _Pragma("unroll") for (int i = 0; i < 2; ++i)                                   \
            _Pragma("unroll") for (int r = 0; r < 4; ++r) {                             \
          const float vb = fmaf(-2.f, acc[i][j][r], e2b);                               \
          const uint32 key = (__float_as_uint(vb) & 0xFFFFFFC0u) | meta;                \
          if (key < k1[i][r]) {                                                         \
            k2[i][r] = k1[i][r];                                                        \
            k1[i][r] = key;                                                             \
          } else if (key < k2[i][r]) {                                                  \
            k2[i][r] = key;                                                             \
          }                                                                             \
        }                                                                               \
      }                                                                                 \
    }                                                                                   \
  }

  // main loop: 4 steps per iteration, ONE barrier per 2 steps.
  // invariant entering block `it` (it % 4 == 0): buffers hold B(it),B(it+1);
  // p0 holds B(it+2), p1 holds B(it+3).
  for (int it = 0; it < ITERS; it += 4) {
    WRITEB(2, p0_)        // B(it+2) -> buf2
    LOADB(p0_, it + 4)
    COMPUTE(0, it)
    WRITEB(3, p1_)        // B(it+3) -> buf3
    LOADB(p1_, it + 5)
    COMPUTE(1, it + 1)
    __syncthreads();
    WRITEB(0, p0_)        // B(it+4) -> buf0
    LOADB(p0_, it + 6)
    COMPUTE(2, it + 2)
    WRITEB(1, p1_)        // B(it+5) -> buf1
    LOADB(p1_, it + 7)
    COMPUTE(3, it + 3)
    __syncthreads();
  }

  // decode packed keys back to (float value, 16-bit global code) pairs
  float bv1[2][4], bv2[2][4];
  uint32 bpi[2][4];
  const uint32 cb_ = (uint32)(cbase + wc * 64 + l15);
#pragma unroll
  for (int i = 0; i < 2; ++i)
#pragma unroll
    for (int r = 0; r < 4; ++r) {
      const uint32 a1 = k1[i][r], a2 = k2[i][r];
      bv1[i][r] = __uint_as_float(a1 & 0xFFFFFFC0u) - BIASF;
      bv2[i][r] = __uint_as_float(a2 & 0xFFFFFFC0u) - BIASF;
      const uint32 c1 = cb_ + ((a1 & 60u) >> 2) * 128u + ((a1 & 3u) << 4);
      const uint32 c2 = cb_ + ((a2 & 60u) >> 2) * 128u + ((a2 & 3u) << 4);
      bpi[i][r] = c1 | (c2 << 16);
    }

  // cross-lane top-2 merge within 16-lane column groups
#pragma unroll
  for (int m = 1; m <= 8; m <<= 1) {
#pragma unroll
    for (int i = 0; i < 2; ++i)
#pragma unroll
      for (int r = 0; r < 4; ++r) {
        const float ov1 = __shfl_xor(bv1[i][r], m, 64);
        const float ov2 = __shfl_xor(bv2[i][r], m, 64);
        const uint32 op = (uint32)__shfl_xor((int)bpi[i][r], m, 64);
        const uint32 ai1 = bpi[i][r] & 0xFFFFu, oi1 = op & 0xFFFFu;
        const bool ol = (ov1 < bv1[i][r]) || (ov1 == bv1[i][r] && oi1 < ai1);
        const float w1 = ol ? ov1 : bv1[i][r];
        const uint32 wi1 = ol ? oi1 : ai1;
        const float w2 = ol ? ov2 : bv2[i][r];
        const uint32 wi2 = ol ? (op >> 16) : (bpi[i][r] >> 16);
        const float l1 = ol ? bv1[i][r] : ov1;
        const uint32 li1 = ol ? ai1 : oi1;
        const bool s2 = (l1 < w2) || (l1 == w2 && li1 < wi2);
        bv1[i][r] = w1;
        bv2[i][r] = s2 ? l1 : w2;
        bpi[i][r] = wi1 | ((s2 ? li1 : wi2) << 16);
      }
  }
  if (l15 == 0) {
    const int slice = c * 2 + wc;
#pragma unroll
    for (int i = 0; i < 2; ++i)
#pragma unroll
      for (int r = 0; r < 4; ++r) {
        const int row = row0 + wr * 32 + i * 16 + lg * 4 + r;
        pt[(size_t)slice * NZ + row] =
            make_float4(bv1[i][r], bv2[i][r], __uint_as_float(bpi[i][r]), 0.f);
      }
  }
}

// ---------------------------------------------------------------- combine + exact fixup + quantize + loss
__global__ void combine_kernel(const float* __restrict__ z, const float* __restrict__ emb,
                               const float* __restrict__ z2, const float* __restrict__ e2,
                               const float4* __restrict__ pt, float* __restrict__ oidx_f,
                               int* __restrict__ oidx_i, float* __restrict__ oq,
                               float* __restrict__ oloss) {
  const int row = blockIdx.x * 4 + (threadIdx.x >> 6);
  const int lane = threadIdx.x & 63;
  const int wid = threadIdx.x >> 6;
  const float4 p = pt[(size_t)(lane & 7) * NZ + row];
  const float v1 = p.x, v2 = p.y;
  const uint32 pk = __float_as_uint(p.z);
  float m = v1;
#pragma unroll
  for (int s = 1; s <= 4; s <<= 1) m = fminf(m, __shfl_xor(m, s, 64));

  const float4 zv = *reinterpret_cast<const float4*>(z + (size_t)row * DD + lane * 4);
  const float z2r = z2[row];
  float bestd = 3.4e38f;
  int besti = KE;
#pragma unroll 1
  for (int cnum = 0; cnum < 16; ++cnum) {
    const int src = (lane & 56) | (cnum >> 1);
    const float vc = __shfl((cnum & 1) ? v2 : v1, src, 64);
    const uint32 pkc = (uint32)__shfl((int)pk, src, 64);
    const int idxc = (cnum & 1) ? (int)(pkc >> 16) : (int)(pkc & 0xFFFFu);
    if (vc < m + THR_GAP) {
      const float4 ev = *reinterpret_cast<const float4*>(emb + (size_t)idxc * DD + lane * 4);
      float s = (zv.x * ev.x + zv.y * ev.y) + (zv.z * ev.z + zv.w * ev.w);
      s = wave_reduce_sum(s);
      const float d = (z2r - 2.f * s) + e2[idxc];
      if (d < bestd || (d == bestd && idxc < besti)) { bestd = d; besti = idxc; }
    }
  }
  if (lane == 0) {
    oidx_f[row] = (float)besti;
    oidx_i[row] = besti;
  }
  // fused quantize + loss (quantized_st == emb[besti] numerically)
  const float4 qv = *reinterpret_cast<const float4*>(emb + (size_t)besti * DD + lane * 4);
  *reinterpret_cast<float4*>(oq + (size_t)row * DD + lane * 4) = qv;
  const float dx = zv.x - qv.x, dy = zv.y - qv.y, dz = zv.z - qv.z, dw = zv.w - qv.w;
  float s = (dx * dx + dy * dy) + (dz * dz + dw * dw);
  s = wave_reduce_sum(s);
  __shared__ float red[4];
  if (lane == 0) red[wid] = s;
  __syncthreads();
  if (threadIdx.x == 0) {
    const float t = (red[0] + red[1]) + (red[2] + red[3]);
    atomicAdd(oloss, t * (1.25f / ((float)NZ * (float)DD)));
  }
}

// ---------------------------------------------------------------- per-code EMA (8 codes/block)
__global__ void perk_kernel(const float* __restrict__ z, const float* __restrict__ ema_cs,
                            const float* __restrict__ ema_es, const int* __restrict__ usage,
                            const int* __restrict__ idx, const float* __restrict__ sema,
                            float* __restrict__ o_emb, float* __restrict__ o_cs,
                            float* __restrict__ o_es, float* __restrict__ o_us) {
  const int k0 = blockIdx.x * 8;
  const int tid = threadIdx.x;
  __shared__ int cnt;
  __shared__ int cnt8[8];
  __shared__ int stot[8];
  __shared__ int rows[2048];
  float acc[8];
#pragma unroll
  for (int q = 0; q < 8; ++q) acc[q] = 0.f;
  if (tid < 8) stot[tid] = 0;
  for (int base = 0; base < NZ; base += 2048) {
    if (tid == 0) cnt = 0;
    if (tid < 8) cnt8[tid] = 0;
    __syncthreads();
#pragma unroll
    for (int t = 0; t < 2048; t += 256) {
      const int r = base + t + tid;
      const int q = idx[r] - k0;
      if ((unsigned)q < 8u) {
        rows[atomicAdd(&cnt, 1)] = (r << 3) | q;
        atomicAdd(&cnt8[q], 1);
      }
    }
    __syncthreads();
    const int cq = cnt;
    if (tid < 8) stot[tid] += cnt8[tid];
    for (int m = 0; m < cq; ++m) {
      const int rr = rows[m];
      const float v = z[(size_t)(rr >> 3) * DD + tid];
      const int q = rr & 7;
#pragma unroll
      for (int qq = 0; qq < 8; ++qq)
        if (qq == q) acc[qq] += v;
    }
    __syncthreads();
  }
  const float n = 0.99f * sema[0] + 0.01f * (float)NZ;
  const float dn = n + (float)KE * 1e-5f;
#pragma unroll
  for (int q = 0; q < 8; ++q) {
    const float ncs = 0.99f * ema_cs[k0 + q] + 0.01f * (float)stot[q];
    const float nes = 0.99f * ema_es[(size_t)(k0 + q) * DD + tid] + 0.01f * acc[q];
    o_es[(size_t)(k0 + q) * DD + tid] = nes;
    o_emb[(size_t)(k0 + q) * DD + tid] = nes / ((ncs + 1e-5f) / dn * n);
  }
  if (tid < 8) {
    o_cs[k0 + tid] = 0.99f * ema_cs[k0 + tid] + 0.01f * (float)stot[tid];
    o_us[k0 + tid] = (float)(usage[k0 + tid] + stot[tid]);
  }
}

// ---------------------------------------------------------------- launch

extern "C" void kernel_launch(void* const* d_in, const int* in_sizes, int n_in,
                              void* d_out, int out_size, void* d_ws, size_t ws_size,
                              hipStream_t stream) {
  const float* z = (const float*)d_in[0];
  const float* emb = (const float*)d_in[1];
  const float* ema_cs = (const float*)d_in[2];
  const float* ema_es = (const float*)d_in[3];
  const int* usage = (const int*)d_in[4];

  float* out = (float*)d_out;
  float* o_idx = out;
  float* o_q = o_idx + NZ;
  float* o_loss = o_q + (size_t)NZ * DD;
  float* o_emb = o_loss + 1;
  float* o_cs = o_emb + (size_t)KE * DD;
  float* o_es = o_cs + KE;
  float* o_us = o_es + (size_t)KE * DD;

  char* w = (char*)d_ws;
  size_t off = 0;
  auto alloc = [&](size_t bytes) -> char* {
    char* r = w + off;
    off = (off + bytes + 255) & ~(size_t)255;
    return r;
  };
  float* ws_e2 = (float*)alloc(KE * 4);
  float* ws_z2 = (float*)alloc(NZ * 4);
  float* ws_sema = (float*)alloc(256);
  int* ws_idx = (int*)alloc(NZ * 4);
  float4* ws_pt = (float4*)alloc((size_t)NSLICE * NZ * 16);
  unsigned short* z_f16 = (unsigned short*)alloc((size_t)NZ * DD * 2);
  unsigned short* e_f16 = (unsigned short*)alloc((size_t)KE * DD * 2);
  (void)ws_size;

  prep_kernel<<<(KE / 4) + (NZ / 4) + 1, 256, 0, stream>>>(emb, e_f16, ws_e2, z, z_f16,
                                                           ws_z2, ema_cs, ws_sema, o_loss);

  mfma_argmin_kernel<<<(NZ / 64) * NCHUNK, 256, 0, stream>>>(z_f16, e_f16, ws_e2, ws_pt);
  combine_kernel<<<NZ / 4, 256, 0, stream>>>(z, emb, ws_z2, ws_e2, ws_pt, o_idx, ws_idx,
                                             o_q, o_loss);
  perk_kernel<<<KE / 8, 256, 0, stream>>>(z, ema_cs, ema_es, usage, ws_idx, ws_sema,
                                          o_emb, o_cs, o_es, o_us);
}